// Round 8
// baseline (379.229 us; speedup 1.0000x reference)
//
#include <hip/hip_runtime.h>

#define INSZ   2048
#define NH1    256
#define NH2    64
#define NB     8
#define BATCH  16384

#define TS        64                 // rows per block-tile
#define MAXTILES  (BATCH / TS)       // 256 (worst case: all samples in one bucket)
#define GRIDX     (NB * MAXTILES)    // 2048, bkt = blockIdx & 7 -> XCD pin heuristic

// W1f: [bkt][kb(64)][cb(16)][lane(64)][8] bf16
#define W1F_U4   (NB * 64 * 16 * 64)        // 524288 uint4
#define W2F_U4   (NB * 8 * 4 * 64)          // 16384 uint4

// ws layout (bytes)
#define META_OFF  0                  // 32 ints: cnt[8], off[8], cursor[8]
#define ORDER_OFF 1024               // 16384 ints
#define W1F_OFF   (1024 + BATCH * 4)            // 66560
#define W2F_OFF   (W1F_OFF + W1F_U4 * 16)       // 8,455,168
#define WS_NEED   (W2F_OFF + W2F_U4 * 16)       // 8,717,312

typedef float f4  __attribute__((ext_vector_type(4)));
typedef float f32x4 __attribute__((ext_vector_type(4)));
typedef short bf16x8 __attribute__((ext_vector_type(8)));

__device__ __forceinline__ unsigned short f2bf(float f) {
    unsigned u = __float_as_uint(f);
    u += 0x7fffu + ((u >> 16) & 1u);   // RNE
    return (unsigned short)(u >> 16);
}
__device__ __forceinline__ float clamp01(float v) { return fminf(fmaxf(v, 0.0f), 1.0f); }
__device__ __forceinline__ unsigned pack2(float a, float b) {
    return (unsigned)f2bf(a) | ((unsigned)f2bf(b) << 16);
}
// keep a value live without cost (rule #17: ablation-via-skip DCEs upstream ops)
__device__ __forceinline__ void keepv(bf16x8 v) { asm volatile("" :: "v"(v)); }

// ============================ pre-pass kernels ============================

__global__ void k_countscan(const int* __restrict__ idx, int* __restrict__ meta) {
    __shared__ int scnt[NB];
    int t = threadIdx.x;
    if (t < NB) scnt[t] = 0;
    __syncthreads();
    int local[NB];
#pragma unroll
    for (int bb = 0; bb < NB; bb++) local[bb] = 0;
    for (int i = t; i < BATCH; i += 1024) {
        int b = idx[i];
#pragma unroll
        for (int bb = 0; bb < NB; bb++) local[bb] += (b == bb) ? 1 : 0;
    }
#pragma unroll
    for (int bb = 0; bb < NB; bb++) {
        int v = local[bb];
        v += __shfl_xor(v, 1);  v += __shfl_xor(v, 2);  v += __shfl_xor(v, 4);
        v += __shfl_xor(v, 8);  v += __shfl_xor(v, 16); v += __shfl_xor(v, 32);
        if ((t & 63) == 0) atomicAdd(&scnt[bb], v);
    }
    __syncthreads();
    if (t == 0) {
        int run = 0;
        for (int b = 0; b < NB; b++) {
            int c = scnt[b];
            meta[b]      = c;
            meta[8 + b]  = run;
            meta[16 + b] = run;   // scatter cursor
            run += c;
        }
    }
}

__global__ void k_scatter(const int* __restrict__ idx, int* __restrict__ meta,
                          int* __restrict__ order) {
    __shared__ int wcnt[16][NB];
    __shared__ int sbase[NB];
    int t = threadIdx.x;
    int i = blockIdx.x * 1024 + t;
    int b = idx[i];
    int wv = t >> 6, lane = t & 63;
    unsigned long long mymask = 0;
#pragma unroll
    for (int bb = 0; bb < NB; bb++) {
        unsigned long long m = __ballot(b == bb);
        if (b == bb) mymask = m;
        if (lane == bb) wcnt[wv][bb] = (int)__popcll(m);
    }
    int myrank = (int)__popcll(mymask & ((1ull << lane) - 1ull));
    __syncthreads();
    if (t < NB) {
        int sum = 0;
        for (int w2 = 0; w2 < 16; w2++) { int c = wcnt[w2][t]; wcnt[w2][t] = sum; sum += c; }
        sbase[t] = atomicAdd(&meta[16 + t], sum);
    }
    __syncthreads();
    order[sbase[b] + wcnt[wv][b] + myrank] = i;
}

// pack W1/W2 into per-lane MFMA B-fragment order (bf16), coalesced reads
__global__ void k_pack(const float* __restrict__ W1, const float* __restrict__ W2,
                       uint4* __restrict__ W1f, uint4* __restrict__ W2f) {
    int u = blockIdx.x * 256 + threadIdx.x;
    if (u < W1F_U4) {
        int k8 = u & 255, row = (u >> 8) & 255, bkt = u >> 16;
        int kb = k8 >> 2, quad = k8 & 3;
        int cb = row >> 4, l15 = row & 15;
        const float* p = W1 + ((size_t)(bkt * NH1 + row)) * INSZ + k8 * 8;
        f4 lo = *(const f4*)p, hi = *(const f4*)(p + 4);
        uint4 o;
        o.x = pack2(lo[0], lo[1]); o.y = pack2(lo[2], lo[3]);
        o.z = pack2(hi[0], hi[1]); o.w = pack2(hi[2], hi[3]);
        W1f[((bkt * 64 + kb) * 16 + cb) * 64 + quad * 16 + l15] = o;
    } else {
        int v = u - W1F_U4;
        if (v >= W2F_U4) return;
        int k8 = v & 31, row = (v >> 5) & 63, bkt = v >> 11;
        int kb2 = k8 >> 2, quad = k8 & 3;
        int cg2 = row >> 4, l15 = row & 15;
        const float* p = W2 + ((size_t)(bkt * NH2 + row)) * NH1 + k8 * 8;
        f4 lo = *(const f4*)p, hi = *(const f4*)(p + 4);
        uint4 o;
        o.x = pack2(lo[0], lo[1]); o.y = pack2(lo[2], lo[3]);
        o.z = pack2(hi[0], hi[1]); o.w = pack2(hi[2], hi[3]);
        W2f[((bkt * 8 + kb2) * 4 + cg2) * 64 + quad * 16 + l15] = o;
    }
}

// ============================ ablation kernel ============================
// DIAGNOSTIC ROUND. Six structural theories (v6-v11) failed: per-K-step time
// is ~3000-3900cy across glds/reg-W, prefetch depth 1/2/4/8, clobber hygiene,
// 1 vs 2 blocks/CU, and 64 vs 9 barriers, while every counter (Mfma/VALU/
// HBM/conflicts) sits <11%. Per Common-mistake #8: ablate before optimizing.
// Base = v8 (best, 80us). Variants (V1-V4 write garbage to out; V0 = full
// kernel runs LAST and overwrites every element -> final output correct):
//   V0 full | V1 no W-loads in loop | V2 no x-staging in loop
//   V3 no MFMA (loads kept live)    | V4 no s_barrier (lgkm wait kept)
// Per-dispatch rocprof rows give each variant's dur/counters -> the dominant
// stream is whichever ablation collapses the time.

template<int V>
__global__ __launch_bounds__(512, 2) void fused_abl(
    const float* __restrict__ x, const int* __restrict__ meta,
    const int* __restrict__ order,
    const short* __restrict__ W1f, const short* __restrict__ W2f,
    const float* __restrict__ b1, const float* __restrict__ b2,
    const float* __restrict__ W3, const float* __restrict__ b3,
    float* __restrict__ out)
{
    constexpr bool DO_WLOAD  = (V != 1);
    constexpr bool DO_XSTAGE = (V != 2);
    constexpr bool DO_MFMA   = (V != 3);
    constexpr bool DO_BARR   = (V != 4);

    const int bkt  = blockIdx.x & 7;
    const int tile = blockIdx.x >> 3;     // identity: 1 active block per CU
    const int cnt  = meta[bkt];
    const int base = tile * TS;
    if (base >= cnt) return;
    const int off = meta[8 + bkt];

    __shared__ short sX[2][TS * 40];     // 2 x 5 KB   x k-step (bf16, stride 40)
    __shared__ short sh1[TS * 264];      // 33.8 KB    h1 (bf16)
    __shared__ float sPart[2][TS];

    const int t = threadIdx.x;
    const int lane = t & 63, w = t >> 6;
    const int l15 = lane & 15, quad = lane >> 4;

    // x staging: thread t -> row t>>3, 4 floats at (t&7)*4
    const int xr = t >> 3, kq = t & 7;
    int ir = base + xr; if (ir > cnt - 1) ir = cnt - 1;
    const float* xtp = x + (size_t)order[off + ir] * INSZ + kq * 4;
    const int sxo = xr * 40 + kq * 4;

    // per-wave W1 fragment pointer: frag (kb, cb=2w+j) at kb*8192 + j*512 (+lane*8)
    const short* wp = W1f + ((size_t)bkt << 19) + (size_t)(2 * w) * 512 + lane * 8;

    f32x4 acc[4][2];
#pragma unroll
    for (int f = 0; f < 4; f++)
#pragma unroll
        for (int j = 0; j < 2; j++) acc[f][j] = (f32x4)0.0f;

    bf16x8 wA0, wA1, wB0, wB1;   // W reg double-buffer: set = kb&1, reloaded at use-step
    f4 xs0, xs1, xs2, xs3;       // x pipeline: slot s holds x(m), m%4==s, depth 4

    // ---- prologue ----
    wA0 = *(const bf16x8*)(wp);
    wA1 = *(const bf16x8*)(wp + 512);
    if constexpr (DO_WLOAD) {
        wB0 = *(const bf16x8*)(wp + 8192);
        wB1 = *(const bf16x8*)(wp + 8192 + 512);
    } else {
        wB0 = wA0; wB1 = wA1;
    }
    {
        f4 x0 = *(const f4*)xtp;
        uint2 pk; pk.x = pack2(x0[0], x0[1]); pk.y = pack2(x0[2], x0[3]);
        *(uint2*)&sX[0][sxo] = pk;
        if constexpr (DO_XSTAGE) {
            xs1 = *(const f4*)(xtp + 32);
            xs2 = *(const f4*)(xtp + 64);
            xs3 = *(const f4*)(xtp + 96);
        } else {
            *(uint2*)&sX[1][sxo] = pk;    // fill buf 1 once; loop never rewrites
        }
    }
    __syncthreads();

#define L1_STEP(KB, XL, XW, WU0, WU1)                                                   \
    {                                                                                   \
        if constexpr (DO_XSTAGE) {                                                      \
            if ((KB) < 60) XL = *(const f4*)(xtp + ((KB) + 4) * 32);                    \
        }                                                                               \
        asm volatile("s_waitcnt lgkmcnt(0)" ::: "memory");                              \
        if constexpr (DO_BARR) __builtin_amdgcn_s_barrier();                            \
        asm volatile("" ::: "memory");                                                  \
        const int P = (KB) & 1;                                                         \
        bf16x8 a0 = *(const bf16x8*)&sX[P][(l15)      * 40 + quad * 8];                 \
        bf16x8 a1 = *(const bf16x8*)&sX[P][(16 + l15) * 40 + quad * 8];                 \
        bf16x8 a2 = *(const bf16x8*)&sX[P][(32 + l15) * 40 + quad * 8];                 \
        bf16x8 a3 = *(const bf16x8*)&sX[P][(48 + l15) * 40 + quad * 8];                 \
        if constexpr (DO_MFMA) {                                                        \
            acc[0][0] = __builtin_amdgcn_mfma_f32_16x16x32_bf16(a0, WU0, acc[0][0], 0,0,0); \
            acc[0][1] = __builtin_amdgcn_mfma_f32_16x16x32_bf16(a0, WU1, acc[0][1], 0,0,0); \
            acc[1][0] = __builtin_amdgcn_mfma_f32_16x16x32_bf16(a1, WU0, acc[1][0], 0,0,0); \
            acc[1][1] = __builtin_amdgcn_mfma_f32_16x16x32_bf16(a1, WU1, acc[1][1], 0,0,0); \
            acc[2][0] = __builtin_amdgcn_mfma_f32_16x16x32_bf16(a2, WU0, acc[2][0], 0,0,0); \
            acc[2][1] = __builtin_amdgcn_mfma_f32_16x16x32_bf16(a2, WU1, acc[2][1], 0,0,0); \
            acc[3][0] = __builtin_amdgcn_mfma_f32_16x16x32_bf16(a3, WU0, acc[3][0], 0,0,0); \
            acc[3][1] = __builtin_amdgcn_mfma_f32_16x16x32_bf16(a3, WU1, acc[3][1], 0,0,0); \
        } else {                                                                        \
            keepv(a0); keepv(a1); keepv(a2); keepv(a3); keepv(WU0); keepv(WU1);         \
        }                                                                               \
        if constexpr (DO_XSTAGE) {                                                      \
            if ((KB) < 63) {                                                            \
                uint2 pk; pk.x = pack2(XW[0], XW[1]); pk.y = pack2(XW[2], XW[3]);       \
                *(uint2*)&sX[P ^ 1][sxo] = pk;                                          \
            }                                                                           \
        }                                                                               \
        if constexpr (DO_WLOAD) {                                                       \
            if ((KB) < 62) {                                                            \
                WU0 = *(const bf16x8*)(wp + (size_t)((KB) + 2) * 8192);                 \
                WU1 = *(const bf16x8*)(wp + (size_t)((KB) + 2) * 8192 + 512);           \
            }                                                                           \
        }                                                                               \
    }

#pragma unroll 1
    for (int kb = 0; kb < 64; kb += 4) {
        L1_STEP(kb + 0, xs0, xs1, wA0, wA1)
        L1_STEP(kb + 1, xs1, xs2, wB0, wB1)
        L1_STEP(kb + 2, xs2, xs3, wA0, wA1)
        L1_STEP(kb + 3, xs3, xs0, wB0, wB1)
    }
#undef L1_STEP

    // ---- layer-1 epilogue: bias + clip01 -> sh1 ----
#pragma unroll
    for (int j = 0; j < 2; j++) {
        int col = w * 32 + j * 16 + l15;
        float bias = b1[bkt * NH1 + col];
#pragma unroll
        for (int f = 0; f < 4; f++)
#pragma unroll
            for (int r = 0; r < 4; r++) {
                int row = f * 16 + quad * 4 + r;
                sh1[row * 264 + col] = (short)f2bf(clamp01(acc[f][j][r] + bias));
            }
    }
    __syncthreads();

    // ---- layer 2: wave w -> h2 rows (w&3)*16..+15, cols (w>>2)*32..+31 ----
    const int rw = w & 3, ch2 = w >> 2;
    f32x4 c2[2];
    c2[0] = (f32x4)0.0f; c2[1] = (f32x4)0.0f;
    const short* w2p = W2f + (size_t)bkt * 16384 + lane * 8;
#pragma unroll
    for (int kb2 = 0; kb2 < 8; kb2++) {
        bf16x8 a2 = *(const bf16x8*)&sh1[(rw * 16 + l15) * 264 + kb2 * 32 + quad * 8];
#pragma unroll
        for (int j = 0; j < 2; j++) {
            bf16x8 bw = *(const bf16x8*)(w2p + (kb2 * 4 + ch2 * 2 + j) * 512);
            c2[j] = __builtin_amdgcn_mfma_f32_16x16x32_bf16(a2, bw, c2[j], 0, 0, 0);
        }
    }

    // ---- layer-2 epilogue + layer-3 partial dot ----
    float s[4] = {0, 0, 0, 0};
#pragma unroll
    for (int j = 0; j < 2; j++) {
        int n2 = (ch2 * 2 + j) * 16 + l15;
        float bias2 = b2[bkt * NH2 + n2];
        float w3v   = W3[bkt * NH2 + n2];
#pragma unroll
        for (int r = 0; r < 4; r++)
            s[r] += clamp01(c2[j][r] + bias2) * w3v;
    }
#pragma unroll
    for (int r = 0; r < 4; r++) {
        float pp = s[r];
        pp += __shfl_xor(pp, 1); pp += __shfl_xor(pp, 2);
        pp += __shfl_xor(pp, 4); pp += __shfl_xor(pp, 8);
        if (l15 == 0) sPart[ch2][rw * 16 + quad * 4 + r] = pp;
    }
    __syncthreads();
    if (t < TS && base + t < cnt)
        out[order[off + base + t]] = sPart[0][t] + sPart[1][t] + b3[bkt];
}

// ============================ naive fallback ============================

__global__ void naive_mlp(const float* __restrict__ x, const int* __restrict__ idx,
                          const float* __restrict__ W1, const float* __restrict__ b1,
                          const float* __restrict__ W2, const float* __restrict__ b2,
                          const float* __restrict__ W3, const float* __restrict__ b3,
                          float* __restrict__ out)
{
    int i = blockIdx.x;
    int b = idx[i];
    __shared__ float sx[INSZ];
    __shared__ float sh1n[NH1];
    __shared__ float sh2n[NH2];
    for (int t = threadIdx.x; t < INSZ; t += 256) sx[t] = x[(size_t)i * INSZ + t];
    __syncthreads();
    int j = threadIdx.x;
    {
        const float* wr = W1 + (size_t)(b * NH1 + j) * INSZ;
        float acc = b1[b * NH1 + j];
        for (int k = 0; k < INSZ; k++) acc += sx[k] * wr[k];
        sh1n[j] = fminf(fmaxf(acc, 0.f), 1.f);
    }
    __syncthreads();
    if (j < NH2) {
        const float* wr = W2 + (size_t)(b * NH2 + j) * NH1;
        float acc = b2[b * NH2 + j];
        for (int k = 0; k < NH1; k++) acc += sh1n[k] * wr[k];
        sh2n[j] = fminf(fmaxf(acc, 0.f), 1.f);
    }
    __syncthreads();
    if (j == 0) {
        float acc = b3[b];
        for (int k = 0; k < NH2; k++) acc += sh2n[k] * W3[b * NH2 + k];
        out[i] = acc;
    }
}

extern "C" void kernel_launch(void* const* d_in, const int* in_sizes, int n_in,
                              void* d_out, int out_size, void* d_ws, size_t ws_size,
                              hipStream_t stream) {
    const float* x  = (const float*)d_in[0];
    const int* bidx = (const int*)d_in[1];
    const float* W1 = (const float*)d_in[2];
    const float* b1 = (const float*)d_in[3];
    const float* W2 = (const float*)d_in[4];
    const float* b2 = (const float*)d_in[5];
    const float* W3 = (const float*)d_in[6];
    const float* b3 = (const float*)d_in[7];
    float* out = (float*)d_out;

    if (ws_size >= (size_t)WS_NEED) {
        char* ws = (char*)d_ws;
        int*   meta  = (int*)(ws + META_OFF);
        int*   order = (int*)(ws + ORDER_OFF);
        uint4* W1f   = (uint4*)(ws + W1F_OFF);
        uint4* W2f   = (uint4*)(ws + W2F_OFF);

        k_countscan<<<1, 1024, 0, stream>>>(bidx, meta);
        k_scatter<<<BATCH / 1024, 1024, 0, stream>>>(bidx, meta, order);
        k_pack<<<(W1F_U4 + W2F_U4) / 256, 256, 0, stream>>>(W1, W2, W1f, W2f);

        // ablation variants (garbage results, overwritten by V0 below)
        fused_abl<1><<<GRIDX, 512, 0, stream>>>(x, meta, order,
                                                (const short*)W1f, (const short*)W2f,
                                                b1, b2, W3, b3, out);
        fused_abl<2><<<GRIDX, 512, 0, stream>>>(x, meta, order,
                                                (const short*)W1f, (const short*)W2f,
                                                b1, b2, W3, b3, out);
        fused_abl<3><<<GRIDX, 512, 0, stream>>>(x, meta, order,
                                                (const short*)W1f, (const short*)W2f,
                                                b1, b2, W3, b3, out);
        fused_abl<4><<<GRIDX, 512, 0, stream>>>(x, meta, order,
                                                (const short*)W1f, (const short*)W2f,
                                                b1, b2, W3, b3, out);
        // full kernel LAST: overwrites every out element -> correct output
        fused_abl<0><<<GRIDX, 512, 0, stream>>>(x, meta, order,
                                                (const short*)W1f, (const short*)W2f,
                                                b1, b2, W3, b3, out);
    } else {
        naive_mlp<<<BATCH, 256, 0, stream>>>(x, bidx, W1, b1, W2, b2, W3, b3, out);
    }
}

// Round 9
// 279.006 us; speedup vs baseline: 1.3592x; 1.3592x over previous
//
#include <hip/hip_runtime.h>

#define INSZ   2048
#define NH1    256
#define NH2    64
#define NB     8
#define BATCH  16384

#define TS        64                 // rows per block-tile
#define MAXTILES  (BATCH / TS)       // 256 (worst case: all samples in one bucket)
#define GRIDX     (NB * MAXTILES)    // 2048, bkt = blockIdx & 7 -> XCD pin heuristic

// W1f: [bkt][kb(64)][cb(16)][lane(64)][8] bf16
#define W1F_U4   (NB * 64 * 16 * 64)        // 524288 uint4
#define W2F_U4   (NB * 8 * 4 * 64)          // 16384 uint4

// ws layout (bytes)
#define META_OFF  0                  // 32 ints: cnt[8], off[8], cursor[8]
#define ORDER_OFF 1024               // 16384 ints
#define W1F_OFF   (1024 + BATCH * 4)            // 66560
#define W2F_OFF   (W1F_OFF + W1F_U4 * 16)       // 8,455,168
#define WS_NEED   (W2F_OFF + W2F_U4 * 16)       // 8,717,312

typedef float f4  __attribute__((ext_vector_type(4)));
typedef float f32x4 __attribute__((ext_vector_type(4)));
typedef short bf16x8 __attribute__((ext_vector_type(8)));

__device__ __forceinline__ unsigned short f2bf(float f) {
    unsigned u = __float_as_uint(f);
    u += 0x7fffu + ((u >> 16) & 1u);   // RNE
    return (unsigned short)(u >> 16);
}
__device__ __forceinline__ float clamp01(float v) { return fminf(fmaxf(v, 0.0f), 1.0f); }
__device__ __forceinline__ unsigned pack2(float a, float b) {
    return (unsigned)f2bf(a) | ((unsigned)f2bf(b) << 16);
}

// ============================ pre-pass kernels ============================

__global__ void k_countscan(const int* __restrict__ idx, int* __restrict__ meta) {
    __shared__ int scnt[NB];
    int t = threadIdx.x;
    if (t < NB) scnt[t] = 0;
    __syncthreads();
    int local[NB];
#pragma unroll
    for (int bb = 0; bb < NB; bb++) local[bb] = 0;
    for (int i = t; i < BATCH; i += 1024) {
        int b = idx[i];
#pragma unroll
        for (int bb = 0; bb < NB; bb++) local[bb] += (b == bb) ? 1 : 0;
    }
#pragma unroll
    for (int bb = 0; bb < NB; bb++) {
        int v = local[bb];
        v += __shfl_xor(v, 1);  v += __shfl_xor(v, 2);  v += __shfl_xor(v, 4);
        v += __shfl_xor(v, 8);  v += __shfl_xor(v, 16); v += __shfl_xor(v, 32);
        if ((t & 63) == 0) atomicAdd(&scnt[bb], v);
    }
    __syncthreads();
    if (t == 0) {
        int run = 0;
        for (int b = 0; b < NB; b++) {
            int c = scnt[b];
            meta[b]      = c;
            meta[8 + b]  = run;
            meta[16 + b] = run;   // scatter cursor
            run += c;
        }
    }
}

__global__ void k_scatter(const int* __restrict__ idx, int* __restrict__ meta,
                          int* __restrict__ order) {
    __shared__ int wcnt[16][NB];
    __shared__ int sbase[NB];
    int t = threadIdx.x;
    int i = blockIdx.x * 1024 + t;
    int b = idx[i];
    int wv = t >> 6, lane = t & 63;
    unsigned long long mymask = 0;
#pragma unroll
    for (int bb = 0; bb < NB; bb++) {
        unsigned long long m = __ballot(b == bb);
        if (b == bb) mymask = m;
        if (lane == bb) wcnt[wv][bb] = (int)__popcll(m);
    }
    int myrank = (int)__popcll(mymask & ((1ull << lane) - 1ull));
    __syncthreads();
    if (t < NB) {
        int sum = 0;
        for (int w2 = 0; w2 < 16; w2++) { int c = wcnt[w2][t]; wcnt[w2][t] = sum; sum += c; }
        sbase[t] = atomicAdd(&meta[16 + t], sum);
    }
    __syncthreads();
    order[sbase[b] + wcnt[wv][b] + myrank] = i;
}

// pack W1/W2 into per-lane MFMA B-fragment order (bf16), coalesced reads
__global__ void k_pack(const float* __restrict__ W1, const float* __restrict__ W2,
                       uint4* __restrict__ W1f, uint4* __restrict__ W2f) {
    int u = blockIdx.x * 256 + threadIdx.x;
    if (u < W1F_U4) {
        int k8 = u & 255, row = (u >> 8) & 255, bkt = u >> 16;
        int kb = k8 >> 2, quad = k8 & 3;
        int cb = row >> 4, l15 = row & 15;
        const float* p = W1 + ((size_t)(bkt * NH1 + row)) * INSZ + k8 * 8;
        f4 lo = *(const f4*)p, hi = *(const f4*)(p + 4);
        uint4 o;
        o.x = pack2(lo[0], lo[1]); o.y = pack2(lo[2], lo[3]);
        o.z = pack2(hi[0], hi[1]); o.w = pack2(hi[2], hi[3]);
        W1f[((bkt * 64 + kb) * 16 + cb) * 64 + quad * 16 + l15] = o;
    } else {
        int v = u - W1F_U4;
        if (v >= W2F_U4) return;
        int k8 = v & 31, row = (v >> 5) & 63, bkt = v >> 11;
        int kb2 = k8 >> 2, quad = k8 & 3;
        int cg2 = row >> 4, l15 = row & 15;
        const float* p = W2 + ((size_t)(bkt * NH2 + row)) * NH1 + k8 * 8;
        f4 lo = *(const f4*)p, hi = *(const f4*)(p + 4);
        uint4 o;
        o.x = pack2(lo[0], lo[1]); o.y = pack2(lo[2], lo[3]);
        o.z = pack2(hi[0], hi[1]); o.w = pack2(hi[2], hi[3]);
        W2f[((bkt * 8 + kb2) * 4 + cg2) * 64 + quad * 16 + l15] = o;
    }
}

// ============================ main fused kernel ============================
// v12: DECOUPLED K-loop. The R7 ablation showed every component (W-loads,
// x-staging, MFMA, barrier) contributes ~equally: the pacer is the serial
// coupled chain, not one stream. v12 removes the links:
//  - x staged fp32 via global_load_lds (1 glds/wave/step, quad-buffered,
//    3 steps of prefetch depth): no reg roundtrip, no ds_write, no lgkm
//    producer chain. Source-chunk XOR involution keeps glds coalesced
//    (128B/row segments) while ds_read offsets (same XOR) are bank-spread.
//  - W fragments loaded via inline-asm global_load_dwordx4: ALL vm ops in
//    the loop are asm/intrinsic-ordered, so hand-counted s_waitcnt vmcnt(N)
//    is exact. Steady state vmcnt(6) (tail 6/5/0); never vmcnt(0) in-loop.
//    Issue-order simulation: glds age 3 steps (~1200cy > HBM), W age 2.
//  - raw s_barrier + sched_barrier(0) per step (rule #18 fence); epilogue
//    scalars preloaded + asm-pinned so no compiler vm op perturbs counts.
//  - v6 wave tiling (2 row-groups x 4 col-groups): per-wave 2 A-frags
//    (fp32->bf16 cvt in regs) x 4 B-frags = 8 MFMA/step; per-CU LDS read
//    32KB/step, under the ~800cy/step HBM pace of x (134MB read once).

#define MFMA16 __builtin_amdgcn_mfma_f32_16x16x32_bf16
#define WLD(D, P) asm volatile("global_load_dwordx4 %0, %1, off" : "=&v"(D) : "v"(P))
#define GLDS16(SRC, DST) __builtin_amdgcn_global_load_lds( \
    (const __attribute__((address_space(1))) unsigned int*)(SRC), \
    (__attribute__((address_space(3))) unsigned int*)(DST), 16, 0, 0)

__global__ __launch_bounds__(512, 2) void fused_v12(
    const float* __restrict__ x, const int* __restrict__ meta,
    const int* __restrict__ order,
    const short* __restrict__ W1f, const short* __restrict__ W2f,
    const float* __restrict__ b1, const float* __restrict__ b2,
    const float* __restrict__ W3, const float* __restrict__ b3,
    float* __restrict__ out)
{
    const int bkt  = blockIdx.x & 7;
    const int tile = blockIdx.x >> 3;     // identity: 1 active block per CU
    const int cnt  = meta[bkt];
    const int base = tile * TS;
    if (base >= cnt) return;
    const int off = meta[8 + bkt];

    __shared__ float sXf[4][2048];       // 4 x 8 KB   x K-step bufs (fp32)
    __shared__ short sh1[TS * 264];      // 33.8 KB    h1 (bf16)
    __shared__ float sPart[2][TS];

    const int t = threadIdx.x;
    const int lane = t & 63, w = t >> 6;
    const int l15 = lane & 15, quad = lane >> 4;
    const int g = w & 1, c4 = w >> 1;     // row-group (32 rows), col-group (64 cols)

    // ---- x staging addresses: wave w stages rows w*8..+7 ----
    // lane: row-in-group = lane>>3, chunk j' = (lane&7) ^ (lane>>3)  (XOR involution)
    const int srow = lane >> 3, sj = (lane & 7) ^ srow;
    int sir = base + w * 8 + srow; if (sir > cnt - 1) sir = cnt - 1;
    const float* xsl = x + (size_t)order[off + sir] * INSZ + sj * 4;
    float* ldst = &sXf[0][0] + w * 256;   // + buf*2048 per step (uniform per wave)

    // ---- A-frag read offsets (bytes, loop-invariant) ----
    // layout: off(r,j) = (r>>3)*1024 + (r&7)*128 + ((j^(r&7))*16
    const int rho = l15 & 7;
    const int grp0 = (g * 32 + l15) >> 3, grp1 = (g * 32 + 16 + l15) >> 3;
    const int cl = (((2 * quad) ^ rho) << 4), ch = (((2 * quad + 1) ^ rho) << 4);
    const int oa0l = grp0 * 1024 + rho * 128 + cl, oa0h = grp0 * 1024 + rho * 128 + ch;
    const int oa1l = grp1 * 1024 + rho * 128 + cl, oa1h = grp1 * 1024 + rho * 128 + ch;

    // per-wave W1 fragment base: frag (kb, cb=c4*4+i) at kb*8192 + i*512 (+lane*8)
    const short* wp = W1f + ((size_t)bkt << 19) + (size_t)(c4 * 4) * 512 + lane * 8;

    // ---- preload + pin epilogue scalars (keeps loop free of stray vm ops) ----
    const int rw = w & 3, ch2 = w >> 2;
    float b1v0 = b1[bkt * NH1 + c4 * 64 + 0 * 16 + l15];
    float b1v1 = b1[bkt * NH1 + c4 * 64 + 1 * 16 + l15];
    float b1v2 = b1[bkt * NH1 + c4 * 64 + 2 * 16 + l15];
    float b1v3 = b1[bkt * NH1 + c4 * 64 + 3 * 16 + l15];
    float b2v0 = b2[bkt * NH2 + (ch2 * 2 + 0) * 16 + l15];
    float b2v1 = b2[bkt * NH2 + (ch2 * 2 + 1) * 16 + l15];
    float w3v0 = W3[bkt * NH2 + (ch2 * 2 + 0) * 16 + l15];
    float w3v1 = W3[bkt * NH2 + (ch2 * 2 + 1) * 16 + l15];
    float b3v  = b3[bkt];
    asm volatile("" :: "v"(b1v0), "v"(b1v1), "v"(b1v2), "v"(b1v3),
                       "v"(b2v0), "v"(b2v1), "v"(w3v0), "v"(w3v1), "v"(b3v));

    f32x4 acc[2][4];
#pragma unroll
    for (int a = 0; a < 2; a++)
#pragma unroll
        for (int i = 0; i < 4; i++) acc[a][i] = (f32x4)0.0f;

    bf16x8 wa0, wa1, wa2, wa3, wb0, wb1, wb2, wb3;   // W sets: A = even kb, B = odd

    // ---- prologue issue order (counts depend on it): W4(0),G0,W4(1),G1,G2 ----
    WLD(wa0, wp);            WLD(wa1, wp + 512);
    WLD(wa2, wp + 1024);     WLD(wa3, wp + 1536);
    GLDS16(xsl, ldst);
    {
        const short* wq = wp + 8192;
        WLD(wb0, wq);        WLD(wb1, wq + 512);
        WLD(wb2, wq + 1024); WLD(wb3, wq + 1536);
    }
    GLDS16(xsl + 32, ldst + 2048);
    GLDS16(xsl + 64, ldst + 4096);
    asm volatile("s_waitcnt vmcnt(6)");      // retire W4(0), G0; keep W4(1),G1,G2
    __builtin_amdgcn_s_barrier();
    __builtin_amdgcn_sched_barrier(0);

    // Step KB: ds_read A(KB) + cvt + 8 MFMA | issue W4(KB+2) into just-freed
    // set | issue glds(KB+3) | vmcnt(VMW) | barrier | sched fence.
#define L1_STEP(KB, BUF, GBUF, W0, W1, W2, W3r, DOW, DOG, VMW)                          \
    {                                                                                   \
        const char* sb = (const char*)&sXf[BUF][0];                                     \
        f4 l0 = *(const f4*)(sb + oa0l), h0 = *(const f4*)(sb + oa0h);                  \
        f4 l1 = *(const f4*)(sb + oa1l), h1 = *(const f4*)(sb + oa1h);                  \
        bf16x8 a0, a1;                                                                  \
        { uint4 u; u.x = pack2(l0[0], l0[1]); u.y = pack2(l0[2], l0[3]);                \
          u.z = pack2(h0[0], h0[1]); u.w = pack2(h0[2], h0[3]);                         \
          a0 = *(bf16x8*)&u; }                                                          \
        { uint4 u; u.x = pack2(l1[0], l1[1]); u.y = pack2(l1[2], l1[3]);                \
          u.z = pack2(h1[0], h1[1]); u.w = pack2(h1[2], h1[3]);                         \
          a1 = *(bf16x8*)&u; }                                                          \
        acc[0][0] = MFMA16(a0, W0, acc[0][0], 0, 0, 0);                                 \
        acc[0][1] = MFMA16(a0, W1, acc[0][1], 0, 0, 0);                                 \
        acc[0][2] = MFMA16(a0, W2, acc[0][2], 0, 0, 0);                                 \
        acc[0][3] = MFMA16(a0, W3r, acc[0][3], 0, 0, 0);                                \
        acc[1][0] = MFMA16(a1, W0, acc[1][0], 0, 0, 0);                                 \
        acc[1][1] = MFMA16(a1, W1, acc[1][1], 0, 0, 0);                                 \
        acc[1][2] = MFMA16(a1, W2, acc[1][2], 0, 0, 0);                                 \
        acc[1][3] = MFMA16(a1, W3r, acc[1][3], 0, 0, 0);                                \
        if (DOW) {                                                                      \
            const short* wq = wp + (size_t)((KB) + 2) * 8192;                           \
            WLD(W0, wq);        WLD(W1, wq + 512);                                      \
            WLD(W2, wq + 1024); WLD(W3r, wq + 1536);                                    \
        }                                                                               \
        if (DOG) GLDS16(xsl + (size_t)((KB) + 3) * 32, ldst + (GBUF) * 2048);           \
        asm volatile("s_waitcnt vmcnt(" #VMW ")");                                      \
        __builtin_amdgcn_s_barrier();                                                   \
        __builtin_amdgcn_sched_barrier(0);                                              \
    }

#pragma unroll 1
    for (int kbb = 0; kbb < 60; kbb += 4) {
        L1_STEP(kbb + 0, 0, 3, wa0, wa1, wa2, wa3, 1, 1, 6)
        L1_STEP(kbb + 1, 1, 0, wb0, wb1, wb2, wb3, 1, 1, 6)
        L1_STEP(kbb + 2, 2, 1, wa0, wa1, wa2, wa3, 1, 1, 6)
        L1_STEP(kbb + 3, 3, 2, wb0, wb1, wb2, wb3, 1, 1, 6)
    }
    // tail: kb = 60 (issues W62,G63), 61 (W63), 62, 63
    L1_STEP(60, 0, 3, wa0, wa1, wa2, wa3, 1, 1, 6)
    L1_STEP(61, 1, 0, wb0, wb1, wb2, wb3, 1, 0, 5)
    L1_STEP(62, 2, 0, wa0, wa1, wa2, wa3, 0, 0, 0)
    L1_STEP(63, 3, 0, wb0, wb1, wb2, wb3, 0, 0, 0)
#undef L1_STEP

    // ---- layer-1 epilogue: bias + clip01 -> sh1 (64 x 256) ----
    {
        float b1v[4] = {b1v0, b1v1, b1v2, b1v3};
#pragma unroll
        for (int i = 0; i < 4; i++) {
            int col = c4 * 64 + i * 16 + l15;
#pragma unroll
            for (int a = 0; a < 2; a++)
#pragma unroll
                for (int r = 0; r < 4; r++) {
                    int row = g * 32 + a * 16 + quad * 4 + r;
                    sh1[row * 264 + col] = (short)f2bf(clamp01(acc[a][i][r] + b1v[i]));
                }
        }
    }
    __syncthreads();

    // ---- layer 2: wave w -> h2 rows (w&3)*16..+15, cols (w>>2)*32..+31 ----
    f32x4 c2[2];
    c2[0] = (f32x4)0.0f; c2[1] = (f32x4)0.0f;
    const short* w2p = W2f + (size_t)bkt * 16384 + lane * 8;
#pragma unroll
    for (int kb2 = 0; kb2 < 8; kb2++) {
        bf16x8 a2 = *(const bf16x8*)&sh1[(rw * 16 + l15) * 264 + kb2 * 32 + quad * 8];
#pragma unroll
        for (int j = 0; j < 2; j++) {
            bf16x8 bw = *(const bf16x8*)(w2p + (kb2 * 4 + ch2 * 2 + j) * 512);
            c2[j] = MFMA16(a2, bw, c2[j], 0, 0, 0);
        }
    }

    // ---- layer-2 epilogue + layer-3 partial dot ----
    float s[4] = {0, 0, 0, 0};
#pragma unroll
    for (int r = 0; r < 4; r++) {
        s[r] += clamp01(c2[0][r] + b2v0) * w3v0;
        s[r] += clamp01(c2[1][r] + b2v1) * w3v1;
    }
#pragma unroll
    for (int r = 0; r < 4; r++) {
        float pp = s[r];
        pp += __shfl_xor(pp, 1); pp += __shfl_xor(pp, 2);
        pp += __shfl_xor(pp, 4); pp += __shfl_xor(pp, 8);
        if (l15 == 0) sPart[ch2][rw * 16 + quad * 4 + r] = pp;
    }
    __syncthreads();
    if (t < TS && base + t < cnt)
        out[order[off + base + t]] = sPart[0][t] + sPart[1][t] + b3v;
}

// ============================ naive fallback ============================

__global__ void naive_mlp(const float* __restrict__ x, const int* __restrict__ idx,
                          const float* __restrict__ W1, const float* __restrict__ b1,
                          const float* __restrict__ W2, const float* __restrict__ b2,
                          const float* __restrict__ W3, const float* __restrict__ b3,
                          float* __restrict__ out)
{
    int i = blockIdx.x;
    int b = idx[i];
    __shared__ float sx[INSZ];
    __shared__ float sh1n[NH1];
    __shared__ float sh2n[NH2];
    for (int t = threadIdx.x; t < INSZ; t += 256) sx[t] = x[(size_t)i * INSZ + t];
    __syncthreads();
    int j = threadIdx.x;
    {
        const float* wr = W1 + (size_t)(b * NH1 + j) * INSZ;
        float acc = b1[b * NH1 + j];
        for (int k = 0; k < INSZ; k++) acc += sx[k] * wr[k];
        sh1n[j] = fminf(fmaxf(acc, 0.f), 1.f);
    }
    __syncthreads();
    if (j < NH2) {
        const float* wr = W2 + (size_t)(b * NH2 + j) * NH1;
        float acc = b2[b * NH2 + j];
        for (int k = 0; k < NH1; k++) acc += sh1n[k] * wr[k];
        sh2n[j] = fminf(fmaxf(acc, 0.f), 1.f);
    }
    __syncthreads();
    if (j == 0) {
        float acc = b3[b];
        for (int k = 0; k < NH2; k++) acc += sh2n[k] * W3[b * NH2 + k];
        out[i] = acc;
    }
}

extern "C" void kernel_launch(void* const* d_in, const int* in_sizes, int n_in,
                              void* d_out, int out_size, void* d_ws, size_t ws_size,
                              hipStream_t stream) {
    const float* x  = (const float*)d_in[0];
    const int* bidx = (const int*)d_in[1];
    const float* W1 = (const float*)d_in[2];
    const float* b1 = (const float*)d_in[3];
    const float* W2 = (const float*)d_in[4];
    const float* b2 = (const float*)d_in[5];
    const float* W3 = (const float*)d_in[6];
    const float* b3 = (const float*)d_in[7];
    float* out = (float*)d_out;

    if (ws_size >= (size_t)WS_NEED) {
        char* ws = (char*)d_ws;
        int*   meta  = (int*)(ws + META_OFF);
        int*   order = (int*)(ws + ORDER_OFF);
        uint4* W1f   = (uint4*)(ws + W1F_OFF);
        uint4* W2f   = (uint4*)(ws + W2F_OFF);

        k_countscan<<<1, 1024, 0, stream>>>(bidx, meta);
        k_scatter<<<BATCH / 1024, 1024, 0, stream>>>(bidx, meta, order);
        k_pack<<<(W1F_U4 + W2F_U4) / 256, 256, 0, stream>>>(W1, W2, W1f, W2f);
        fused_v12<<<GRIDX, 512, 0, stream>>>(x, meta, order,
                                             (const short*)W1f, (const short*)W2f,
                                             b1, b2, W3, b3, out);
    } else {
        naive_mlp<<<BATCH, 256, 0, stream>>>(x, bidx, W1, b1, W2, b2, W3, b3, out);
    }
}

// Round 10
// 275.303 us; speedup vs baseline: 1.3775x; 1.0134x over previous
//
#include <hip/hip_runtime.h>

#define INSZ   2048
#define NH1    256
#define NH2    64
#define NB     8
#define BATCH  16384

#define TS        32                 // rows per block-tile
#define MAXTILES  (BATCH / TS)       // 512 (worst case: all samples in one bucket)
#define GRIDX     (NB * MAXTILES)    // 4096, bkt = blockIdx & 7 -> XCD pin heuristic

// W1f: [bkt][kb(64)][cb(16)][lane(64)][8] bf16
#define W1F_U4   (NB * 64 * 16 * 64)        // 524288 uint4
#define W2F_U4   (NB * 8 * 4 * 64)          // 16384 uint4

// ws layout (bytes)
#define META_OFF  0                  // 32 ints: cnt[8], off[8], cursor[8]
#define ORDER_OFF 1024               // 16384 ints
#define W1F_OFF   (1024 + BATCH * 4)            // 66560
#define W2F_OFF   (W1F_OFF + W1F_U4 * 16)       // 8,455,168
#define WS_NEED   (W2F_OFF + W2F_U4 * 16)       // 8,717,312

typedef float f4  __attribute__((ext_vector_type(4)));
typedef float f32x4 __attribute__((ext_vector_type(4)));
typedef short bf16x8 __attribute__((ext_vector_type(8)));

__device__ __forceinline__ unsigned short f2bf(float f) {
    unsigned u = __float_as_uint(f);
    u += 0x7fffu + ((u >> 16) & 1u);   // RNE
    return (unsigned short)(u >> 16);
}
__device__ __forceinline__ float clamp01(float v) { return fminf(fmaxf(v, 0.0f), 1.0f); }
__device__ __forceinline__ unsigned pack2(float a, float b) {
    return (unsigned)f2bf(a) | ((unsigned)f2bf(b) << 16);
}
__device__ __forceinline__ bf16x8 mk8(uint2 lo, uint2 hi) {
    union { unsigned u[4]; bf16x8 v; } r;
    r.u[0] = lo.x; r.u[1] = lo.y; r.u[2] = hi.x; r.u[3] = hi.y;
    return r.v;
}

// ============================ pre-pass kernels ============================

__global__ void k_countscan(const int* __restrict__ idx, int* __restrict__ meta) {
    __shared__ int scnt[NB];
    int t = threadIdx.x;
    if (t < NB) scnt[t] = 0;
    __syncthreads();
    int local[NB];
#pragma unroll
    for (int bb = 0; bb < NB; bb++) local[bb] = 0;
    for (int i = t; i < BATCH; i += 1024) {
        int b = idx[i];
#pragma unroll
        for (int bb = 0; bb < NB; bb++) local[bb] += (b == bb) ? 1 : 0;
    }
#pragma unroll
    for (int bb = 0; bb < NB; bb++) {
        int v = local[bb];
        v += __shfl_xor(v, 1);  v += __shfl_xor(v, 2);  v += __shfl_xor(v, 4);
        v += __shfl_xor(v, 8);  v += __shfl_xor(v, 16); v += __shfl_xor(v, 32);
        if ((t & 63) == 0) atomicAdd(&scnt[bb], v);
    }
    __syncthreads();
    if (t == 0) {
        int run = 0;
        for (int b = 0; b < NB; b++) {
            int c = scnt[b];
            meta[b]      = c;
            meta[8 + b]  = run;
            meta[16 + b] = run;   // scatter cursor
            run += c;
        }
    }
}

__global__ void k_scatter(const int* __restrict__ idx, int* __restrict__ meta,
                          int* __restrict__ order) {
    __shared__ int wcnt[16][NB];
    __shared__ int sbase[NB];
    int t = threadIdx.x;
    int i = blockIdx.x * 1024 + t;
    int b = idx[i];
    int wv = t >> 6, lane = t & 63;
    unsigned long long mymask = 0;
#pragma unroll
    for (int bb = 0; bb < NB; bb++) {
        unsigned long long m = __ballot(b == bb);
        if (b == bb) mymask = m;
        if (lane == bb) wcnt[wv][bb] = (int)__popcll(m);
    }
    int myrank = (int)__popcll(mymask & ((1ull << lane) - 1ull));
    __syncthreads();
    if (t < NB) {
        int sum = 0;
        for (int w2 = 0; w2 < 16; w2++) { int c = wcnt[w2][t]; wcnt[w2][t] = sum; sum += c; }
        sbase[t] = atomicAdd(&meta[16 + t], sum);
    }
    __syncthreads();
    order[sbase[b] + wcnt[wv][b] + myrank] = i;
}

// pack W1/W2 into per-lane MFMA B-fragment order (bf16), coalesced reads
__global__ void k_pack(const float* __restrict__ W1, const float* __restrict__ W2,
                       uint4* __restrict__ W1f, uint4* __restrict__ W2f) {
    int u = blockIdx.x * 256 + threadIdx.x;
    if (u < W1F_U4) {
        int k8 = u & 255, row = (u >> 8) & 255, bkt = u >> 16;
        int kb = k8 >> 2, quad = k8 & 3;
        int cb = row >> 4, l15 = row & 15;
        const float* p = W1 + ((size_t)(bkt * NH1 + row)) * INSZ + k8 * 8;
        f4 lo = *(const f4*)p, hi = *(const f4*)(p + 4);
        uint4 o;
        o.x = pack2(lo[0], lo[1]); o.y = pack2(lo[2], lo[3]);
        o.z = pack2(hi[0], hi[1]); o.w = pack2(hi[2], hi[3]);
        W1f[((bkt * 64 + kb) * 16 + cb) * 64 + quad * 16 + l15] = o;
    } else {
        int v = u - W1F_U4;
        if (v >= W2F_U4) return;
        int k8 = v & 31, row = (v >> 5) & 63, bkt = v >> 11;
        int kb2 = k8 >> 2, quad = k8 & 3;
        int cg2 = row >> 4, l15 = row & 15;
        const float* p = W2 + ((size_t)(bkt * NH2 + row)) * NH1 + k8 * 8;
        f4 lo = *(const f4*)p, hi = *(const f4*)(p + 4);
        uint4 o;
        o.x = pack2(lo[0], lo[1]); o.y = pack2(lo[2], lo[3]);
        o.z = pack2(hi[0], hi[1]); o.w = pack2(hi[2], hi[3]);
        W2f[((bkt * 8 + kb2) * 4 + cg2) * 64 + quad * 16 + l15] = o;
    }
}

// ============================ main fused kernel ============================
// v13: PHASE-SEPARATED x. Root cause of the 3000cy/step invariant (v6-v12):
// vmcnt is a single in-order counter shared by W (L2, ~250cy, needed every
// step) and x (HBM gather, ~900-1500cy, needed steps later). Every W wait
// force-retires older x loads only 1-2 steps old -> each step eats HBM
// latency. R7 ablation confirms: removing EITHER stream collapses the loop.
// Fix: ZERO outstanding x loads during the K-loop. K is split into 4 slabs
// of 16 steps; per slab all x cols are staged into LDS (bf16, K-major,
// pad-36 rows -> conflict-free b64 reads, 36KB static) behind a barrier,
// THEN 16 steps run with only W on the vm counter -> compiler W waits gate
// nothing else, no barriers inside. 54KB LDS -> 2 blocks/CU, so one block's
// staging overlaps the other's compute. TS=32: 8 col-waves (32 cols each),
// per step 2 A-frags x 2 B-frags = 4 MFMA/wave. Layer 2/3 = v10's verified
// 32-row code.

#define MFMA16 __builtin_amdgcn_mfma_f32_16x16x32_bf16

__global__ __launch_bounds__(512, 2) void fused_v13(
    const float* __restrict__ x, const int* __restrict__ meta,
    const int* __restrict__ order,
    const short* __restrict__ W1f, const short* __restrict__ W2f,
    const float* __restrict__ b1, const float* __restrict__ b2,
    const float* __restrict__ W3, const float* __restrict__ b3,
    float* __restrict__ out)
{
    const int bkt  = blockIdx.x & 7;
    const int tile = blockIdx.x >> 3;     // identity mapping
    const int cnt  = meta[bkt];
    const int base = tile * TS;
    if (base >= cnt) return;
    const int off = meta[8 + bkt];

    __shared__ short sX[16 * 1152];      // 36 KB  [kbL(16)][row(32)][36 shorts]
    __shared__ short sh1[TS * 264];      // 16.9 KB h1 (bf16)
    __shared__ float sPart[4][TS];       // 0.5 KB

    const int t = threadIdx.x;
    const int lane = t & 63, w = t >> 6;
    const int l15 = lane & 15, quad = lane >> 4;

    // staging: thread t -> row t>>4, col sub-lane t&15
    const int xr = t >> 4, c16 = t & 15;
    int ir = base + xr; if (ir > cnt - 1) ir = cnt - 1;
    const float* xrow = x + (size_t)order[off + ir] * INSZ;

    // wave w owns cols w*32..+31: frags cb = 2w, 2w+1
    const short* wp = W1f + ((size_t)bkt << 19) + (size_t)(2 * w) * 512 + lane * 8;

    f32x4 acc[2][2];
#pragma unroll
    for (int f = 0; f < 2; f++)
#pragma unroll
        for (int j = 0; j < 2; j++) acc[f][j] = (f32x4)0.0f;

#pragma unroll 1
    for (int s = 0; s < 4; s++) {
        // ---- stage slab s: cols s*512 .. +511 -> sX (bf16 K-major) ----
        if (s) __syncthreads();          // protect sX from previous subloop readers
#pragma unroll
        for (int j = 0; j < 8; j++) {
            const int col = s * 512 + c16 * 4 + j * 64;        // 4 consecutive cols
            f4 v = *(const f4*)(xrow + col);
            const int kbL = (col >> 5) & 15, ko = col & 31;
            uint2 pk; pk.x = pack2(v[0], v[1]); pk.y = pack2(v[2], v[3]);
            *(uint2*)&sX[kbL * 1152 + xr * 36 + ko] = pk;
        }
        __syncthreads();

        // ---- 16 K-steps, pure-LDS A, W-only vm traffic, NO barriers ----
#pragma unroll
        for (int kbL = 0; kbL < 16; kbL++) {
            const int kb = s * 16 + kbL;
            const int ab = kbL * 1152 + l15 * 36 + quad * 8;
            uint2 lo0 = *(const uint2*)&sX[ab];
            uint2 hi0 = *(const uint2*)&sX[ab + 4];
            uint2 lo1 = *(const uint2*)&sX[ab + 576];          // +16 rows
            uint2 hi1 = *(const uint2*)&sX[ab + 580];
            bf16x8 a0 = mk8(lo0, hi0);
            bf16x8 a1 = mk8(lo1, hi1);
            bf16x8 w0 = *(const bf16x8*)(wp + (size_t)kb * 8192);
            bf16x8 w1 = *(const bf16x8*)(wp + (size_t)kb * 8192 + 512);
            acc[0][0] = MFMA16(a0, w0, acc[0][0], 0, 0, 0);
            acc[0][1] = MFMA16(a0, w1, acc[0][1], 0, 0, 0);
            acc[1][0] = MFMA16(a1, w0, acc[1][0], 0, 0, 0);
            acc[1][1] = MFMA16(a1, w1, acc[1][1], 0, 0, 0);
        }
    }

    // ---- layer-1 epilogue: bias + clip01 -> sh1 (32 rows x 256 cols) ----
#pragma unroll
    for (int j = 0; j < 2; j++) {
        int col = w * 32 + j * 16 + l15;
        float bias = b1[bkt * NH1 + col];
#pragma unroll
        for (int f = 0; f < 2; f++)
#pragma unroll
            for (int r = 0; r < 4; r++) {
                int row = f * 16 + quad * 4 + r;
                sh1[row * 264 + col] = (short)f2bf(clamp01(acc[f][j][r] + bias));
            }
    }
    __syncthreads();

    // ---- layer 2: wave w -> h2 rows (w&1)*16..+15, cols (w>>1)*16..+15 ----
    const int rw = w & 1, cg2 = w >> 1;
    f32x4 c2 = (f32x4)0.0f;
    const short* w2p = W2f + (size_t)bkt * 16384 + lane * 8;
#pragma unroll
    for (int kb2 = 0; kb2 < 8; kb2++) {
        bf16x8 a2 = *(const bf16x8*)&sh1[(rw * 16 + l15) * 264 + kb2 * 32 + quad * 8];
        bf16x8 bw = *(const bf16x8*)(w2p + (kb2 * 4 + cg2) * 512);
        c2 = MFMA16(a2, bw, c2, 0, 0, 0);
    }

    // ---- layer-2 epilogue + layer-3 partial dot ----
    {
        int n2 = cg2 * 16 + l15;
        float bias2 = b2[bkt * NH2 + n2];
        float w3v   = W3[bkt * NH2 + n2];
        float sacc[4];
#pragma unroll
        for (int r = 0; r < 4; r++)
            sacc[r] = clamp01(c2[r] + bias2) * w3v;
#pragma unroll
        for (int r = 0; r < 4; r++) {
            float pp = sacc[r];
            pp += __shfl_xor(pp, 1); pp += __shfl_xor(pp, 2);
            pp += __shfl_xor(pp, 4); pp += __shfl_xor(pp, 8);
            if (l15 == 0) sPart[cg2][rw * 16 + quad * 4 + r] = pp;
        }
    }
    __syncthreads();
    if (t < TS && base + t < cnt)
        out[order[off + base + t]] =
            sPart[0][t] + sPart[1][t] + sPart[2][t] + sPart[3][t] + b3[bkt];
}

// ============================ naive fallback ============================

__global__ void naive_mlp(const float* __restrict__ x, const int* __restrict__ idx,
                          const float* __restrict__ W1, const float* __restrict__ b1,
                          const float* __restrict__ W2, const float* __restrict__ b2,
                          const float* __restrict__ W3, const float* __restrict__ b3,
                          float* __restrict__ out)
{
    int i = blockIdx.x;
    int b = idx[i];
    __shared__ float sx[INSZ];
    __shared__ float sh1n[NH1];
    __shared__ float sh2n[NH2];
    for (int t = threadIdx.x; t < INSZ; t += 256) sx[t] = x[(size_t)i * INSZ + t];
    __syncthreads();
    int j = threadIdx.x;
    {
        const float* wr = W1 + (size_t)(b * NH1 + j) * INSZ;
        float acc = b1[b * NH1 + j];
        for (int k = 0; k < INSZ; k++) acc += sx[k] * wr[k];
        sh1n[j] = fminf(fmaxf(acc, 0.f), 1.f);
    }
    __syncthreads();
    if (j < NH2) {
        const float* wr = W2 + (size_t)(b * NH2 + j) * NH1;
        float acc = b2[b * NH2 + j];
        for (int k = 0; k < NH1; k++) acc += sh1n[k] * wr[k];
        sh2n[j] = fminf(fmaxf(acc, 0.f), 1.f);
    }
    __syncthreads();
    if (j == 0) {
        float acc = b3[b];
        for (int k = 0; k < NH2; k++) acc += sh2n[k] * W3[b * NH2 + k];
        out[i] = acc;
    }
}

extern "C" void kernel_launch(void* const* d_in, const int* in_sizes, int n_in,
                              void* d_out, int out_size, void* d_ws, size_t ws_size,
                              hipStream_t stream) {
    const float* x  = (const float*)d_in[0];
    const int* bidx = (const int*)d_in[1];
    const float* W1 = (const float*)d_in[2];
    const float* b1 = (const float*)d_in[3];
    const float* W2 = (const float*)d_in[4];
    const float* b2 = (const float*)d_in[5];
    const float* W3 = (const float*)d_in[6];
    const float* b3 = (const float*)d_in[7];
    float* out = (float*)d_out;

    if (ws_size >= (size_t)WS_NEED) {
        char* ws = (char*)d_ws;
        int*   meta  = (int*)(ws + META_OFF);
        int*   order = (int*)(ws + ORDER_OFF);
        uint4* W1f   = (uint4*)(ws + W1F_OFF);
        uint4* W2f   = (uint4*)(ws + W2F_OFF);

        k_countscan<<<1, 1024, 0, stream>>>(bidx, meta);
        k_scatter<<<BATCH / 1024, 1024, 0, stream>>>(bidx, meta, order);
        k_pack<<<(W1F_U4 + W2F_U4) / 256, 256, 0, stream>>>(W1, W2, W1f, W2f);
        fused_v13<<<GRIDX, 512, 0, stream>>>(x, meta, order,
                                             (const short*)W1f, (const short*)W2f,
                                             b1, b2, W3, b3, out);
    } else {
        naive_mlp<<<BATCH, 256, 0, stream>>>(x, bidx, W1, b1, W2, b2, W3, b3, out);
    }
}